// Round 2
// 830.866 us; speedup vs baseline: 1.0662x; 1.0662x over previous
//
#include <hip/hip_runtime.h>
#include <hip/hip_bf16.h>

// B=128, S=1024, F=512, H=32, G=128. rows = B*S = 131072.
// Pipeline: k1: x->xg (3 fused GEMMs, bf16 MFMA, x split hi/lo for precision)
//           k2: LSTM scan (fp32, 1 wave per batch, readlane matvec,
//               LDS triple-buffered xg chunks via global_load_lds, packed fma)
//           k3: hs->out (2 fused GEMMs, bf16 MFMA)

typedef __attribute__((ext_vector_type(8))) __bf16 bf16x8;
typedef __attribute__((ext_vector_type(4))) __bf16 bf16x4;
typedef __attribute__((ext_vector_type(4))) float floatx4;
typedef __attribute__((ext_vector_type(2))) float floatx2;

// ---------------------------------------------------------------- kernel 1
// 64 rows/block, 4 waves (16 rows each). LDS carve (51712 B):
//  region A: [0)      w1T[32][520] (33280B)  -> later w2T[64][40]@0 + wxT[128][72]@5120
//  region B: [33280)  xsh[64][72] + xsl[64][72]@42496 -> later h1s[64][40]@33280 + h2s[64][72]@38400
__global__ __launch_bounds__(256) void k_mlp_xg(
    const float* __restrict__ x,  const float* __restrict__ W1, const float* __restrict__ b1,
    const float* __restrict__ W2, const float* __restrict__ b2,
    const float* __restrict__ Wx, const float* __restrict__ bl,
    float* __restrict__ xg)
{
    __shared__ __align__(16) char smem[51712];
    __bf16* w1T = (__bf16*)smem;             // [32][520]
    __bf16* w2T = (__bf16*)smem;             // [64][40]
    __bf16* wxT = (__bf16*)(smem + 5120);    // [128][72]
    __bf16* xsh = (__bf16*)(smem + 33280);   // [64][72]  (K-chunk of 64)
    __bf16* xsl = (__bf16*)(smem + 42496);   // [64][72]
    __bf16* h1s = (__bf16*)(smem + 33280);   // [64][40]
    __bf16* h2s = (__bf16*)(smem + 38400);   // [64][72]

    const int tid  = threadIdx.x;
    const int lane = tid & 63, w = tid >> 6;
    const int quad = lane >> 4, col = lane & 15;
    const int row0 = blockIdx.x * 64;
    const int m     = w * 16 + col;          // A-frag row (block-local)
    const int rbase = w * 16 + quad * 4;     // C-frag row base (block-local)
    const floatx4 fzero = {0.f, 0.f, 0.f, 0.f};

    // stage W1^T as bf16 (once; whole K=512)
    for (int i = tid; i < 512 * 32; i += 256) {
        int k = i >> 5, n = i & 31;
        w1T[n * 520 + k] = (__bf16)W1[i];
    }
    auto stage_x = [&](int kc) {
        for (int i4 = tid; i4 < 1024; i4 += 256) {
            int f = i4 << 2; int r = f >> 6, cc = f & 63;
            float4 v = *(const float4*)(x + (size_t)(row0 + r) * 512 + kc * 64 + cc);
            __bf16 h0 = (__bf16)v.x, h1 = (__bf16)v.y, h2 = (__bf16)v.z, h3 = (__bf16)v.w;
            bf16x4 hi = {h0, h1, h2, h3};
            bf16x4 lo = {(__bf16)(v.x - (float)h0), (__bf16)(v.y - (float)h1),
                         (__bf16)(v.z - (float)h2), (__bf16)(v.w - (float)h3)};
            *(bf16x4*)(xsh + r * 72 + cc) = hi;
            *(bf16x4*)(xsl + r * 72 + cc) = lo;
        }
    };
    stage_x(0);
    __syncthreads();

    // ---- layer1: h1 = tanh(x @ W1 + b1), K=512 (8 chunks of 64), N=32 (2 tiles)
    floatx4 acc1[2] = {fzero, fzero};
    for (int kc = 0; kc < 8; ++kc) {
#pragma unroll
        for (int ks = 0; ks < 2; ++ks) {
            int ko = ks * 32 + quad * 8;
            bf16x8 ah = *(const bf16x8*)(xsh + m * 72 + ko);
            bf16x8 al = *(const bf16x8*)(xsl + m * 72 + ko);
            int kg = kc * 64 + ko;
#pragma unroll
            for (int nt = 0; nt < 2; ++nt) {
                bf16x8 bfr = *(const bf16x8*)(w1T + (nt * 16 + col) * 520 + kg);
                acc1[nt] = __builtin_amdgcn_mfma_f32_16x16x32_bf16(ah, bfr, acc1[nt], 0, 0, 0);
                acc1[nt] = __builtin_amdgcn_mfma_f32_16x16x32_bf16(al, bfr, acc1[nt], 0, 0, 0);
            }
        }
        if (kc < 7) { __syncthreads(); stage_x(kc + 1); __syncthreads(); }
    }
    __syncthreads();   // all waves done reading xs / w1T

#pragma unroll
    for (int nt = 0; nt < 2; ++nt) {
        float bb = b1[nt * 16 + col];
#pragma unroll
        for (int r = 0; r < 4; ++r)
            h1s[(rbase + r) * 40 + nt * 16 + col] = (__bf16)tanhf(acc1[nt][r] + bb);
    }
    // stage W2^T and Wx^T (region A, w1T dead)
    for (int i = tid; i < 32 * 64; i += 256)  { int k = i >> 6, n = i & 63;  w2T[n * 40 + k] = (__bf16)W2[i]; }
    for (int i = tid; i < 64 * 128; i += 256) { int k = i >> 7, n = i & 127; wxT[n * 72 + k] = (__bf16)Wx[i]; }
    __syncthreads();

    // ---- layer2: h2 = tanh(h1 @ W2 + b2), K=32, N=64 (4 tiles)
    bf16x8 a2 = *(const bf16x8*)(h1s + m * 40 + quad * 8);
    floatx4 acc2[4];
#pragma unroll
    for (int nt = 0; nt < 4; ++nt) {
        bf16x8 bfr = *(const bf16x8*)(w2T + (nt * 16 + col) * 40 + quad * 8);
        acc2[nt] = __builtin_amdgcn_mfma_f32_16x16x32_bf16(a2, bfr, fzero, 0, 0, 0);
    }
#pragma unroll
    for (int nt = 0; nt < 4; ++nt) {
        float bb = b2[nt * 16 + col];
#pragma unroll
        for (int r = 0; r < 4; ++r)
            h2s[(rbase + r) * 72 + nt * 16 + col] = (__bf16)tanhf(acc2[nt][r] + bb);
    }
    // no barrier: each wave reads only its own 16 rows of h2s

    // ---- layer3: xg = h2 @ Wx + bl, K=64 (2 steps), N=128 (8 tiles)
    floatx4 acc3[8];
#pragma unroll
    for (int nt = 0; nt < 8; ++nt) acc3[nt] = fzero;
#pragma unroll
    for (int ks = 0; ks < 2; ++ks) {
        int ko = ks * 32 + quad * 8;
        bf16x8 a3 = *(const bf16x8*)(h2s + m * 72 + ko);
#pragma unroll
        for (int nt = 0; nt < 8; ++nt) {
            bf16x8 bfr = *(const bf16x8*)(wxT + (nt * 16 + col) * 72 + ko);
            acc3[nt] = __builtin_amdgcn_mfma_f32_16x16x32_bf16(a3, bfr, acc3[nt], 0, 0, 0);
        }
    }
#pragma unroll
    for (int nt = 0; nt < 8; ++nt) {
        float bb = bl[nt * 16 + col];
#pragma unroll
        for (int r = 0; r < 4; ++r)
            xg[(size_t)(row0 + rbase + r) * 128 + nt * 16 + col] = acc3[nt][r] + bb;
    }
}

// ---------------------------------------------------------------- kernel 2
// One wave per batch (128 blocks x 64 threads). Lane l owns gates l and l+64
// (Wh columns packed as float2 in 64 VGPRs). h_j lives in lane j (j<32).
// Gate order: [i(0:32) f(32:64) g(64:96) o(96:128)].
//
// R4 vs R3: revert v_permlane32_swap_b32 -> __shfl(x, l^32) (R3 failed
// correctness; the two-"+v"-operand asm with discarded halves is the prime
// suspect — semantics/regalloc unverified). Keep:
//  - xg fed from LDS: triple-buffered 32-step chunks (16KB each) staged with
//    global_load_lds dwordx4 (16 insts / 32 steps). Removes per-step global
//    addressing + clamp + vmcnt exposure; per-step reads are ds_read with
//    ~120cy latency, hidden by the 4-deep register ring.
//  - matvec packed as float2 accum (whA/whB interleaved) -> v_pk_fma_f32
//    with readlane-SGPR broadcast: halves matvec issue.
#define RLANE(v, k) __uint_as_float(__builtin_amdgcn_readlane(__float_as_uint(v), (k)))

__global__ __launch_bounds__(64) void k_lstm(
    const float* __restrict__ xg, const float* __restrict__ Wh,
    float* __restrict__ hs)
{
    __shared__ __align__(16) float xbuf[3][32 * 128];   // 48 KB, 3 chunks of 32 steps

    const int b = blockIdx.x;
    const int l = threadIdx.x;
    const float* xgb = xg + (size_t)b * 1024 * 128;
    float* hsb = hs + (size_t)b * 1024 * 32;

    floatx2 wh[32];
#pragma unroll
    for (int k = 0; k < 32; ++k)
        wh[k] = floatx2{Wh[k * 128 + l], Wh[k * 128 + 64 + l]};

    // a1 = (l<32) ? 2*s1-1 : s1  done branch-free: a1 = s1*m1 + c1
    const float sc1 = (l < 32) ? 2.0f : 1.0f;    // tanh(x)=2*sigmoid(2x)-1
    const float m1  = (l < 32) ? 2.0f : 1.0f;
    const float c1  = (l < 32) ? -1.0f : 0.0f;

    // async stage one 32-step chunk (16 KB = 16 x 1KB dwordx4 DMAs)
    auto stage_chunk = [&](int cidx) {
        const float* src = xgb + (size_t)cidx * 4096 + l * 4;
        float* dst = &xbuf[cidx % 3][0];
#pragma unroll
        for (int i = 0; i < 16; ++i)
            __builtin_amdgcn_global_load_lds(src + i * 256, dst + i * 256, 16, 0, 0);
    };

    stage_chunk(0); stage_chunk(1); stage_chunk(2);
    // 48 DMAs outstanding; wait until only chunk2's 16 remain -> chunks 0,1 resident
    asm volatile("s_waitcnt vmcnt(16)" ::: "memory");

    float c = 0.f, h = 0.f;

    // register ring, depth 4, fed from LDS
    float xr0[4], xr1[4];
#pragma unroll
    for (int p = 0; p < 4; ++p) {
        xr0[p] = xbuf[0][p * 128 + l];
        xr1[p] = xbuf[0][p * 128 + 64 + l];
    }

#pragma unroll 1
    for (int ch = 0; ch < 32; ++ch) {
        const float* bufc = xbuf[ch % 3];
        const float* bufn = xbuf[(ch + 1) % 3];
#pragma unroll 1
        for (int s = 0; s < 32; s += 4) {
#pragma unroll
            for (int u = 0; u < 4; ++u) {
                const int tc = ch * 32 + s + u;
                float x0 = xr0[u], x1 = xr1[u];
                // refill ring for step tc+4 (rows 32..35 spill into next chunk's
                // buffer; resident by construction. Last 4 steps load stale data
                // that is never consumed.)
                {
                    int rn = s + u + 4;
                    const float* p = (rn < 32) ? (bufc + rn * 128) : (bufn + (rn - 32) * 128);
                    xr0[u] = p[l];
                    xr1[u] = p[64 + l];
                }
                floatx2 pa = {x0, x1};
                floatx2 pb = {0.f, 0.f}, pc = {0.f, 0.f}, pd = {0.f, 0.f};
#pragma unroll
                for (int k = 0; k < 32; k += 4) {
                    float h0 = RLANE(h, k);
                    float h1 = RLANE(h, k + 1);
                    float h2 = RLANE(h, k + 2);
                    float h3 = RLANE(h, k + 3);
                    pa += wh[k]     * h0;
                    pb += wh[k + 1] * h1;
                    pc += wh[k + 2] * h2;
                    pd += wh[k + 3] * h3;
                }
                floatx2 pe = (pa + pb) + (pc + pd);
                float pre0 = pe.x;                       // i (l<32) / f (l>=32)
                float pre1 = pe.y;                       // g (l<32) / o (l>=32)
                float a0 = __builtin_amdgcn_rcpf(1.0f + __expf(-pre0));       // sigmoid(i|f)
                float s1 = __builtin_amdgcn_rcpf(1.0f + __expf(-sc1 * pre1));
                float a1 = __builtin_fmaf(s1, m1, c1);                        // tanh(g) | sigmoid(o)
                float f_ = __shfl(a0, l ^ 32);   // lane j<32 gets f_j
                float o_ = __shfl(a1, l ^ 32);   // lane j<32 gets o_j
                c = f_ * c + a0 * a1;            // valid in lanes 0-31 (upper: garbage, never read)
                float e = __expf(-2.0f * c);
                float th = (1.0f - e) * __builtin_amdgcn_rcpf(1.0f + e);
                h = o_ * th;
                if (l < 32) hsb[tc * 32 + l] = h;
            }
        }
        if (ch + 3 < 32) {
            // refill the buffer just vacated (chunk ch's); wait until only those
            // 16 DMAs remain -> chunk ch+2 resident before chunk ch+1's tail
            // prefetch touches it.
            stage_chunk(ch + 3);
            asm volatile("s_waitcnt vmcnt(16)" ::: "memory");
        } else {
            asm volatile("s_waitcnt vmcnt(0)" ::: "memory");
        }
    }
}

// ---------------------------------------------------------------- kernel 3
// 64 rows/block. LDS: hss[64][40]@0, w3T[64][40]@5120, h3s[64][72]@10240,
//                     w4T[128][72]@19456  (total 37888 B)
__global__ __launch_bounds__(256) void k_tail(
    const float* __restrict__ hs, const float* __restrict__ W3, const float* __restrict__ b3,
    const float* __restrict__ W4, const float* __restrict__ b4,
    float* __restrict__ out)
{
    __shared__ __align__(16) char smem[37888];
    __bf16* hss = (__bf16*)smem;
    __bf16* w3T = (__bf16*)(smem + 5120);
    __bf16* h3s = (__bf16*)(smem + 10240);
    __bf16* w4T = (__bf16*)(smem + 19456);

    const int tid  = threadIdx.x;
    const int lane = tid & 63, w = tid >> 6;
    const int quad = lane >> 4, col = lane & 15;
    const int row0 = blockIdx.x * 64;
    const int m     = w * 16 + col;
    const int rbase = w * 16 + quad * 4;
    const floatx4 fzero = {0.f, 0.f, 0.f, 0.f};

    for (int i4 = tid; i4 < 512; i4 += 256) {
        int f = i4 << 2; int r = f >> 5, cc = f & 31;
        float4 v = *(const float4*)(hs + (size_t)(row0 + r) * 32 + cc);
        bf16x4 hv = {(__bf16)v.x, (__bf16)v.y, (__bf16)v.z, (__bf16)v.w};
        *(bf16x4*)(hss + r * 40 + cc) = hv;
    }
    for (int i = tid; i < 32 * 64; i += 256) { int k = i >> 6, n = i & 63; w3T[n * 40 + k] = (__bf16)W3[i]; }
    __syncthreads();

    // ---- h3 = tanh(hs @ W3 + b3), K=32, N=64
    bf16x8 a3 = *(const bf16x8*)(hss + m * 40 + quad * 8);
    floatx4 acc3[4];
#pragma unroll
    for (int nt = 0; nt < 4; ++nt) {
        bf16x8 bfr = *(const bf16x8*)(w3T + (nt * 16 + col) * 40 + quad * 8);
        acc3[nt] = __builtin_amdgcn_mfma_f32_16x16x32_bf16(a3, bfr, fzero, 0, 0, 0);
    }
#pragma unroll
    for (int nt = 0; nt < 4; ++nt) {
        float bb = b3[nt * 16 + col];
#pragma unroll
        for (int r = 0; r < 4; ++r)
            h3s[(rbase + r) * 72 + nt * 16 + col] = (__bf16)tanhf(acc3[nt][r] + bb);
    }

    // ---- out = h3 @ W4 + b4, K=64, N=512 in 4 column chunks of 128
    for (int oc = 0; oc < 4; ++oc) {
        __syncthreads();   // prior chunk's B-frag reads done before w4T rewrite
        for (int i4 = tid; i4 < 2048; i4 += 256) {
            int f = i4 << 2; int k = f >> 7, cc = f & 127;
            float4 v = *(const float4*)(W4 + (size_t)k * 512 + oc * 128 + cc);
            w4T[(cc + 0) * 72 + k] = (__bf16)v.x;
            w4T[(cc + 1) * 72 + k] = (__bf16)v.y;
            w4T[(cc + 2) * 72 + k] = (__bf16)v.z;
            w4T[(cc + 3) * 72 + k] = (__bf16)v.w;
        }
        __syncthreads();

        floatx4 acc4[8];
#pragma unroll
        for (int nt = 0; nt < 8; ++nt) acc4[nt] = fzero;
#pragma unroll
        for (int ks = 0; ks < 2; ++ks) {
            int ko = ks * 32 + quad * 8;
            bf16x8 a4 = *(const bf16x8*)(h3s + m * 72 + ko);
#pragma unroll
            for (int nt = 0; nt < 8; ++nt) {
                bf16x8 bfr = *(const bf16x8*)(w4T + (nt * 16 + col) * 72 + ko);
                acc4[nt] = __builtin_amdgcn_mfma_f32_16x16x32_bf16(a4, bfr, acc4[nt], 0, 0, 0);
            }
        }
#pragma unroll
        for (int nt = 0; nt < 8; ++nt) {
            float bb = b4[oc * 128 + nt * 16 + col];
#pragma unroll
            for (int r = 0; r < 4; ++r)
                out[(size_t)(row0 + rbase + r) * 512 + oc * 128 + nt * 16 + col] = acc4[nt][r] + bb;
        }
    }
}

// ---------------------------------------------------------------- launch
extern "C" void kernel_launch(void* const* d_in, const int* in_sizes, int n_in,
                              void* d_out, int out_size, void* d_ws, size_t ws_size,
                              hipStream_t stream)
{
    (void)in_sizes; (void)n_in; (void)out_size;
    const float* x  = (const float*)d_in[0];
    const float* W1 = (const float*)d_in[1];
    const float* b1 = (const float*)d_in[2];
    const float* W2 = (const float*)d_in[3];
    const float* b2 = (const float*)d_in[4];
    const float* Wx = (const float*)d_in[5];
    const float* Wh = (const float*)d_in[6];
    const float* bl = (const float*)d_in[7];
    const float* W3 = (const float*)d_in[8];
    const float* b3 = (const float*)d_in[9];
    const float* W4 = (const float*)d_in[10];
    const float* b4 = (const float*)d_in[11];
    float* out = (float*)d_out;

    const size_t hsElems = (size_t)128 * 1024 * 32;    // 16 MB
    const size_t xgElems = (size_t)128 * 1024 * 128;   // 64 MB
    float* hs = (float*)d_ws;
    float* xg = (ws_size >= (hsElems + xgElems) * sizeof(float))
                    ? hs + hsElems
                    : out;   // stash xg in d_out; k3 rewrites d_out only after hs is done

    k_mlp_xg<<<2048, 256, 0, stream>>>(x, W1, b1, W2, b2, Wx, bl, xg);
    k_lstm<<<128, 64, 0, stream>>>(xg, Wh, hs);
    k_tail<<<2048, 256, 0, stream>>>(hs, W3, b3, W4, b4, out);
}

// Round 3
// 818.941 us; speedup vs baseline: 1.0818x; 1.0146x over previous
//
#include <hip/hip_runtime.h>
#include <hip/hip_bf16.h>

// B=128, S=1024, F=512, H=32, G=128. rows = B*S = 131072.
// Pipeline: k1: x->xg (3 fused GEMMs, bf16 MFMA, x split hi/lo for precision,
//               A-fragments streamed from global — no x staging, 3 barriers total)
//           k2: LSTM scan (fp32, 1 wave per batch, readlane matvec,
//               LDS triple-buffered xg chunks via global_load_lds, packed fma)
//           k3: hs->out (2 fused GEMMs, bf16 MFMA, 256 rows/block, vectorized
//               W4 transpose staging)

typedef __attribute__((ext_vector_type(8))) __bf16 bf16x8;
typedef __attribute__((ext_vector_type(4))) __bf16 bf16x4;
typedef __attribute__((ext_vector_type(4))) float floatx4;
typedef __attribute__((ext_vector_type(2))) float floatx2;

// ---------------------------------------------------------------- kernel 1
// 64 rows/block, 4 waves (16 rows each). LDS carve (47616 B):
//  region A: [0)      w1T[32][520] (33280B)  -> later w2T[64][40]@0 + wxT[128][72]@5120
//  region B: [33280)  h1s[64][40]@33280 + h2s[64][72]@38400
// x is NOT staged: each lane builds its A-frag (hi/lo split) from 2 dwordx4
// global loads. Per (kc,ks) the 4 quads of a wave cover a full 128B line of
// each of the 16 rows -> coalesced; K-loop has no barriers.
__global__ __launch_bounds__(256) void k_mlp_xg(
    const float* __restrict__ x,  const float* __restrict__ W1, const float* __restrict__ b1,
    const float* __restrict__ W2, const float* __restrict__ b2,
    const float* __restrict__ Wx, const float* __restrict__ bl,
    float* __restrict__ xg)
{
    __shared__ __align__(16) char smem[47616];
    __bf16* w1T = (__bf16*)smem;             // [32][520]
    __bf16* w2T = (__bf16*)smem;             // [64][40]
    __bf16* wxT = (__bf16*)(smem + 5120);    // [128][72]
    __bf16* h1s = (__bf16*)(smem + 33280);   // [64][40]
    __bf16* h2s = (__bf16*)(smem + 38400);   // [64][72]

    const int tid  = threadIdx.x;
    const int lane = tid & 63, w = tid >> 6;
    const int quad = lane >> 4, col = lane & 15;
    const int row0 = blockIdx.x * 64;
    const int m     = w * 16 + col;          // A-frag row (block-local)
    const int rbase = w * 16 + quad * 4;     // C-frag row base (block-local)
    const floatx4 fzero = {0.f, 0.f, 0.f, 0.f};

    // stage W1^T as bf16 (once; whole K=512)
    for (int i = tid; i < 512 * 32; i += 256) {
        int k = i >> 5, n = i & 31;
        w1T[n * 520 + k] = (__bf16)W1[i];
    }
    __syncthreads();

    // ---- layer1: h1 = tanh(x @ W1 + b1), K=512 (8 chunks of 64), N=32 (2 tiles)
    const float* xrow = x + (size_t)(row0 + m) * 512;
    floatx4 acc1[2] = {fzero, fzero};
    for (int kc = 0; kc < 8; ++kc) {
#pragma unroll
        for (int ks = 0; ks < 2; ++ks) {
            int kg = kc * 64 + ks * 32 + quad * 8;
            float4 v0 = *(const float4*)(xrow + kg);
            float4 v1 = *(const float4*)(xrow + kg + 4);
            __bf16 e0 = (__bf16)v0.x, e1 = (__bf16)v0.y, e2 = (__bf16)v0.z, e3 = (__bf16)v0.w;
            __bf16 e4 = (__bf16)v1.x, e5 = (__bf16)v1.y, e6 = (__bf16)v1.z, e7 = (__bf16)v1.w;
            bf16x8 ah = {e0, e1, e2, e3, e4, e5, e6, e7};
            bf16x8 al = {(__bf16)(v0.x - (float)e0), (__bf16)(v0.y - (float)e1),
                         (__bf16)(v0.z - (float)e2), (__bf16)(v0.w - (float)e3),
                         (__bf16)(v1.x - (float)e4), (__bf16)(v1.y - (float)e5),
                         (__bf16)(v1.z - (float)e6), (__bf16)(v1.w - (float)e7)};
#pragma unroll
            for (int nt = 0; nt < 2; ++nt) {
                bf16x8 bfr = *(const bf16x8*)(w1T + (nt * 16 + col) * 520 + kg);
                acc1[nt] = __builtin_amdgcn_mfma_f32_16x16x32_bf16(ah, bfr, acc1[nt], 0, 0, 0);
                acc1[nt] = __builtin_amdgcn_mfma_f32_16x16x32_bf16(al, bfr, acc1[nt], 0, 0, 0);
            }
        }
    }
    __syncthreads();   // all waves done reading w1T

#pragma unroll
    for (int nt = 0; nt < 2; ++nt) {
        float bb = b1[nt * 16 + col];
#pragma unroll
        for (int r = 0; r < 4; ++r)
            h1s[(rbase + r) * 40 + nt * 16 + col] = (__bf16)tanhf(acc1[nt][r] + bb);
    }
    // stage W2^T and Wx^T (region A, w1T dead)
    for (int i = tid; i < 32 * 64; i += 256)  { int k = i >> 6, n = i & 63;  w2T[n * 40 + k] = (__bf16)W2[i]; }
    for (int i = tid; i < 64 * 128; i += 256) { int k = i >> 7, n = i & 127; wxT[n * 72 + k] = (__bf16)Wx[i]; }
    __syncthreads();

    // ---- layer2: h2 = tanh(h1 @ W2 + b2), K=32, N=64 (4 tiles)
    bf16x8 a2 = *(const bf16x8*)(h1s + m * 40 + quad * 8);
    floatx4 acc2[4];
#pragma unroll
    for (int nt = 0; nt < 4; ++nt) {
        bf16x8 bfr = *(const bf16x8*)(w2T + (nt * 16 + col) * 40 + quad * 8);
        acc2[nt] = __builtin_amdgcn_mfma_f32_16x16x32_bf16(a2, bfr, fzero, 0, 0, 0);
    }
#pragma unroll
    for (int nt = 0; nt < 4; ++nt) {
        float bb = b2[nt * 16 + col];
#pragma unroll
        for (int r = 0; r < 4; ++r)
            h2s[(rbase + r) * 72 + nt * 16 + col] = (__bf16)tanhf(acc2[nt][r] + bb);
    }
    // no barrier: each wave reads only its own 16 rows of h2s

    // ---- layer3: xg = h2 @ Wx + bl, K=64 (2 steps), N=128 (8 tiles)
    floatx4 acc3[8];
#pragma unroll
    for (int nt = 0; nt < 8; ++nt) acc3[nt] = fzero;
#pragma unroll
    for (int ks = 0; ks < 2; ++ks) {
        int ko = ks * 32 + quad * 8;
        bf16x8 a3 = *(const bf16x8*)(h2s + m * 72 + ko);
#pragma unroll
        for (int nt = 0; nt < 8; ++nt) {
            bf16x8 bfr = *(const bf16x8*)(wxT + (nt * 16 + col) * 72 + ko);
            acc3[nt] = __builtin_amdgcn_mfma_f32_16x16x32_bf16(a3, bfr, acc3[nt], 0, 0, 0);
        }
    }
#pragma unroll
    for (int nt = 0; nt < 8; ++nt) {
        float bb = bl[nt * 16 + col];
#pragma unroll
        for (int r = 0; r < 4; ++r)
            xg[(size_t)(row0 + rbase + r) * 128 + nt * 16 + col] = acc3[nt][r] + bb;
    }
}

// ---------------------------------------------------------------- kernel 2
// One wave per batch (128 blocks x 64 threads). Lane l owns gates l and l+64
// (Wh columns packed as float2 in 64 VGPRs). h_j lives in lane j (j<32).
// Gate order: [i(0:32) f(32:64) g(64:96) o(96:128)].
// UNCHANGED from R4 (verified): LDS triple-buffered xg via global_load_lds,
// packed v_pk_fma matvec, shfl(l^32) cross-half swap.
#define RLANE(v, k) __uint_as_float(__builtin_amdgcn_readlane(__float_as_uint(v), (k)))

__global__ __launch_bounds__(64) void k_lstm(
    const float* __restrict__ xg, const float* __restrict__ Wh,
    float* __restrict__ hs)
{
    __shared__ __align__(16) float xbuf[3][32 * 128];   // 48 KB, 3 chunks of 32 steps

    const int b = blockIdx.x;
    const int l = threadIdx.x;
    const float* xgb = xg + (size_t)b * 1024 * 128;
    float* hsb = hs + (size_t)b * 1024 * 32;

    floatx2 wh[32];
#pragma unroll
    for (int k = 0; k < 32; ++k)
        wh[k] = floatx2{Wh[k * 128 + l], Wh[k * 128 + 64 + l]};

    // a1 = (l<32) ? 2*s1-1 : s1  done branch-free: a1 = s1*m1 + c1
    const float sc1 = (l < 32) ? 2.0f : 1.0f;    // tanh(x)=2*sigmoid(2x)-1
    const float m1  = (l < 32) ? 2.0f : 1.0f;
    const float c1  = (l < 32) ? -1.0f : 0.0f;

    // async stage one 32-step chunk (16 KB = 16 x 1KB dwordx4 DMAs)
    auto stage_chunk = [&](int cidx) {
        const float* src = xgb + (size_t)cidx * 4096 + l * 4;
        float* dst = &xbuf[cidx % 3][0];
#pragma unroll
        for (int i = 0; i < 16; ++i)
            __builtin_amdgcn_global_load_lds(src + i * 256, dst + i * 256, 16, 0, 0);
    };

    stage_chunk(0); stage_chunk(1); stage_chunk(2);
    // 48 DMAs outstanding; wait until only chunk2's 16 remain -> chunks 0,1 resident
    asm volatile("s_waitcnt vmcnt(16)" ::: "memory");

    float c = 0.f, h = 0.f;

    // register ring, depth 4, fed from LDS
    float xr0[4], xr1[4];
#pragma unroll
    for (int p = 0; p < 4; ++p) {
        xr0[p] = xbuf[0][p * 128 + l];
        xr1[p] = xbuf[0][p * 128 + 64 + l];
    }

#pragma unroll 1
    for (int ch = 0; ch < 32; ++ch) {
        const float* bufc = xbuf[ch % 3];
        const float* bufn = xbuf[(ch + 1) % 3];
#pragma unroll 1
        for (int s = 0; s < 32; s += 4) {
#pragma unroll
            for (int u = 0; u < 4; ++u) {
                const int tc = ch * 32 + s + u;
                float x0 = xr0[u], x1 = xr1[u];
                // refill ring for step tc+4 (rows 32..35 spill into next chunk's
                // buffer; resident by construction. Last 4 steps load stale data
                // that is never consumed.)
                {
                    int rn = s + u + 4;
                    const float* p = (rn < 32) ? (bufc + rn * 128) : (bufn + (rn - 32) * 128);
                    xr0[u] = p[l];
                    xr1[u] = p[64 + l];
                }
                floatx2 pa = {x0, x1};
                floatx2 pb = {0.f, 0.f}, pc = {0.f, 0.f}, pd = {0.f, 0.f};
#pragma unroll
                for (int k = 0; k < 32; k += 4) {
                    float h0 = RLANE(h, k);
                    float h1 = RLANE(h, k + 1);
                    float h2 = RLANE(h, k + 2);
                    float h3 = RLANE(h, k + 3);
                    pa += wh[k]     * h0;
                    pb += wh[k + 1] * h1;
                    pc += wh[k + 2] * h2;
                    pd += wh[k + 3] * h3;
                }
                floatx2 pe = (pa + pb) + (pc + pd);
                float pre0 = pe.x;                       // i (l<32) / f (l>=32)
                float pre1 = pe.y;                       // g (l<32) / o (l>=32)
                float a0 = __builtin_amdgcn_rcpf(1.0f + __expf(-pre0));       // sigmoid(i|f)
                float s1 = __builtin_amdgcn_rcpf(1.0f + __expf(-sc1 * pre1));
                float a1 = __builtin_fmaf(s1, m1, c1);                        // tanh(g) | sigmoid(o)
                float f_ = __shfl(a0, l ^ 32);   // lane j<32 gets f_j
                float o_ = __shfl(a1, l ^ 32);   // lane j<32 gets o_j
                c = f_ * c + a0 * a1;            // valid in lanes 0-31 (upper: garbage, never read)
                float e = __expf(-2.0f * c);
                float th = (1.0f - e) * __builtin_amdgcn_rcpf(1.0f + e);
                h = o_ * th;
                if (l < 32) hsb[tc * 32 + l] = h;
            }
        }
        if (ch + 3 < 32) {
            // refill the buffer just vacated (chunk ch's); wait until only those
            // 16 DMAs remain -> chunk ch+2 resident before chunk ch+1's tail
            // prefetch touches it.
            stage_chunk(ch + 3);
            asm volatile("s_waitcnt vmcnt(16)" ::: "memory");
        } else {
            asm volatile("s_waitcnt vmcnt(0)" ::: "memory");
        }
    }
}

// ---------------------------------------------------------------- kernel 3
// 256 rows/block (512 blocks), 4 waves (64 rows each). LDS carve (62464 B):
//  h3s[256][72] @0      (36864)
//  hss[256][40] @36864  (20480)  -> dead after GEMM-W3; w4T[128][76] @36864 (19456)
//  w3T[64][40]  @57344  (5120)
// W4 transpose staged per 128-col chunk with 4k x 4n per thread, ds_write_b64.
// w4T stride 76 -> conflict-free B-frag reads, 4-way (cheap) staging writes.
__global__ __launch_bounds__(256, 2) void k_tail(
    const float* __restrict__ hs, const float* __restrict__ W3, const float* __restrict__ b3,
    const float* __restrict__ W4, const float* __restrict__ b4,
    float* __restrict__ out)
{
    __shared__ __align__(16) char smem[62464];
    __bf16* h3s = (__bf16*)smem;             // [256][72]
    __bf16* hss = (__bf16*)(smem + 36864);   // [256][40]
    __bf16* w4T = (__bf16*)(smem + 36864);   // [128][76] (reuses hss region)
    __bf16* w3T = (__bf16*)(smem + 57344);   // [64][40]

    const int tid  = threadIdx.x;
    const int lane = tid & 63, w = tid >> 6;
    const int quad = lane >> 4, col = lane & 15;
    const int row0 = blockIdx.x * 256;
    const floatx4 fzero = {0.f, 0.f, 0.f, 0.f};

    // stage hs rows (256 x 32 fp32 -> bf16) and W3^T
    for (int i4 = tid; i4 < 2048; i4 += 256) {
        int f = i4 << 2; int r = f >> 5, cc = f & 31;
        float4 v = *(const float4*)(hs + (size_t)(row0 + r) * 32 + cc);
        bf16x4 hv = {(__bf16)v.x, (__bf16)v.y, (__bf16)v.z, (__bf16)v.w};
        *(bf16x4*)(hss + r * 40 + cc) = hv;
    }
    for (int i = tid; i < 32 * 64; i += 256) { int k = i >> 6, n = i & 63; w3T[n * 40 + k] = (__bf16)W3[i]; }
    __syncthreads();

    // ---- h3 = tanh(hs @ W3 + b3), K=32, N=64; 4 m-tiles per wave
#pragma unroll
    for (int mt = 0; mt < 4; ++mt) {
        const int m     = w * 64 + mt * 16 + col;
        const int rbase = w * 64 + mt * 16 + quad * 4;
        bf16x8 a3 = *(const bf16x8*)(hss + m * 40 + quad * 8);
        floatx4 acc3[4];
#pragma unroll
        for (int nt = 0; nt < 4; ++nt) {
            bf16x8 bfr = *(const bf16x8*)(w3T + (nt * 16 + col) * 40 + quad * 8);
            acc3[nt] = __builtin_amdgcn_mfma_f32_16x16x32_bf16(a3, bfr, fzero, 0, 0, 0);
        }
#pragma unroll
        for (int nt = 0; nt < 4; ++nt) {
            float bb = b3[nt * 16 + col];
#pragma unroll
            for (int r = 0; r < 4; ++r)
                h3s[(rbase + r) * 72 + nt * 16 + col] = (__bf16)tanhf(acc3[nt][r] + bb);
        }
    }

    // ---- out = h3 @ W4 + b4, K=64, N=512 in 4 column chunks of 128
    for (int oc = 0; oc < 4; ++oc) {
        __syncthreads();   // prior chunk's B-frag reads (and hss reads, oc=0) done
        // stage w4T[n][k] for this 128-col chunk: 4k x 4n per thread, 2 iters
        for (int it = tid; it < 512; it += 256) {
            int k0 = (it >> 5) << 2;          // 0..60
            int n0 = (it & 31) << 2;          // 0..124
            const float* wp = W4 + (size_t)k0 * 512 + oc * 128 + n0;
            float4 r0 = *(const float4*)(wp);
            float4 r1 = *(const float4*)(wp + 512);
            float4 r2 = *(const float4*)(wp + 1024);
            float4 r3 = *(const float4*)(wp + 1536);
            bf16x4 c0 = {(__bf16)r0.x, (__bf16)r1.x, (__bf16)r2.x, (__bf16)r3.x};
            bf16x4 c1 = {(__bf16)r0.y, (__bf16)r1.y, (__bf16)r2.y, (__bf16)r3.y};
            bf16x4 c2 = {(__bf16)r0.z, (__bf16)r1.z, (__bf16)r2.z, (__bf16)r3.z};
            bf16x4 c3 = {(__bf16)r0.w, (__bf16)r1.w, (__bf16)r2.w, (__bf16)r3.w};
            *(bf16x4*)(w4T + (n0 + 0) * 76 + k0) = c0;
            *(bf16x4*)(w4T + (n0 + 1) * 76 + k0) = c1;
            *(bf16x4*)(w4T + (n0 + 2) * 76 + k0) = c2;
            *(bf16x4*)(w4T + (n0 + 3) * 76 + k0) = c3;
        }
        __syncthreads();

        floatx4 acc4[4][8];
#pragma unroll
        for (int mt = 0; mt < 4; ++mt)
#pragma unroll
            for (int nt = 0; nt < 8; ++nt) acc4[mt][nt] = fzero;
#pragma unroll
        for (int ks = 0; ks < 2; ++ks) {
            int ko = ks * 32 + quad * 8;
#pragma unroll
            for (int mt = 0; mt < 4; ++mt) {
                bf16x8 a4 = *(const bf16x8*)(h3s + (w * 64 + mt * 16 + col) * 72 + ko);
#pragma unroll
                for (int nt = 0; nt < 8; ++nt) {
                    bf16x8 bfr = *(const bf16x8*)(w4T + (nt * 16 + col) * 76 + ko);
                    acc4[mt][nt] = __builtin_amdgcn_mfma_f32_16x16x32_bf16(a4, bfr, acc4[mt][nt], 0, 0, 0);
                }
            }
        }
#pragma unroll
        for (int nt = 0; nt < 8; ++nt) {
            float bb = b4[oc * 128 + nt * 16 + col];
#pragma unroll
            for (int mt = 0; mt < 4; ++mt) {
                const int rbase = row0 + w * 64 + mt * 16 + quad * 4;
#pragma unroll
                for (int r = 0; r < 4; ++r)
                    out[(size_t)(rbase + r) * 512 + oc * 128 + nt * 16 + col] = acc4[mt][nt][r] + bb;
            }
        }
    }
}

// ---------------------------------------------------------------- launch
extern "C" void kernel_launch(void* const* d_in, const int* in_sizes, int n_in,
                              void* d_out, int out_size, void* d_ws, size_t ws_size,
                              hipStream_t stream)
{
    (void)in_sizes; (void)n_in; (void)out_size;
    const float* x  = (const float*)d_in[0];
    const float* W1 = (const float*)d_in[1];
    const float* b1 = (const float*)d_in[2];
    const float* W2 = (const float*)d_in[3];
    const float* b2 = (const float*)d_in[4];
    const float* Wx = (const float*)d_in[5];
    const float* Wh = (const float*)d_in[6];
    const float* bl = (const float*)d_in[7];
    const float* W3 = (const float*)d_in[8];
    const float* b3 = (const float*)d_in[9];
    const float* W4 = (const float*)d_in[10];
    const float* b4 = (const float*)d_in[11];
    float* out = (float*)d_out;

    const size_t hsElems = (size_t)128 * 1024 * 32;    // 16 MB
    const size_t xgElems = (size_t)128 * 1024 * 128;   // 64 MB
    float* hs = (float*)d_ws;
    float* xg = (ws_size >= (hsElems + xgElems) * sizeof(float))
                    ? hs + hsElems
                    : out;   // stash xg in d_out; k3 rewrites d_out only after hs is done

    k_mlp_xg<<<2048, 256, 0, stream>>>(x, W1, b1, W2, b2, Wx, bl, xg);
    k_lstm<<<128, 64, 0, stream>>>(xg, Wh, hs);
    k_tail<<<512, 256, 0, stream>>>(hs, W3, b3, W4, b4, out);
}

// Round 4
// 786.740 us; speedup vs baseline: 1.1260x; 1.0409x over previous
//
#include <hip/hip_runtime.h>
#include <hip/hip_bf16.h>

// B=128, S=1024, F=512, H=32, G=128. rows = B*S = 131072.
// Pipeline: k1: x->xg (3 fused GEMMs, bf16 MFMA, x split hi/lo for precision,
//               A-fragments streamed from global with explicit 1-chunk prefetch)
//           k2: LSTM scan (fp32, 1 wave per batch, readlane matvec,
//               LDS triple-buffered xg chunks via global_load_lds, packed fma,
//               permlane32_swap cross-half broadcast)
//           k3: hs->out (2 fused GEMMs, bf16 MFMA, 256 rows/block, vectorized
//               W4 transpose staging)

typedef __attribute__((ext_vector_type(8))) __bf16 bf16x8;
typedef __attribute__((ext_vector_type(4))) __bf16 bf16x4;
typedef __attribute__((ext_vector_type(4))) float floatx4;
typedef __attribute__((ext_vector_type(2))) float floatx2;
typedef __attribute__((ext_vector_type(2))) unsigned int uint2v;

// ---------------------------------------------------------------- kernel 1
// 64 rows/block, 4 waves (16 rows each). LDS carve (47616 B):
//  region A: [0)      w1T[32][520] (33280B)  -> later w2T[64][40]@0 + wxT[128][72]@5120
//  region B: [33280)  h1s[64][40]@33280 + h2s[64][72]@38400
// x is NOT staged: each lane builds its A-frag (hi/lo split) from 2 dwordx4
// global loads, explicitly prefetched one K-chunk ahead (tests the
// latency-exposure hypothesis; arithmetic identical to R3).
__global__ __launch_bounds__(256) void k_mlp_xg(
    const float* __restrict__ x,  const float* __restrict__ W1, const float* __restrict__ b1,
    const float* __restrict__ W2, const float* __restrict__ b2,
    const float* __restrict__ Wx, const float* __restrict__ bl,
    float* __restrict__ xg)
{
    __shared__ __align__(16) char smem[47616];
    __bf16* w1T = (__bf16*)smem;             // [32][520]
    __bf16* w2T = (__bf16*)smem;             // [64][40]
    __bf16* wxT = (__bf16*)(smem + 5120);    // [128][72]
    __bf16* h1s = (__bf16*)(smem + 33280);   // [64][40]
    __bf16* h2s = (__bf16*)(smem + 38400);   // [64][72]

    const int tid  = threadIdx.x;
    const int lane = tid & 63, w = tid >> 6;
    const int quad = lane >> 4, col = lane & 15;
    const int row0 = blockIdx.x * 64;
    const int m     = w * 16 + col;          // A-frag row (block-local)
    const int rbase = w * 16 + quad * 4;     // C-frag row base (block-local)
    const floatx4 fzero = {0.f, 0.f, 0.f, 0.f};

    // stage W1^T as bf16 (once; whole K=512)
    for (int i = tid; i < 512 * 32; i += 256) {
        int k = i >> 5, n = i & 31;
        w1T[n * 520 + k] = (__bf16)W1[i];
    }
    __syncthreads();

    // ---- layer1: h1 = tanh(x @ W1 + b1), K=512 (8 chunks of 64), N=32 (2 tiles)
    const float* xrow = x + (size_t)(row0 + m) * 512 + quad * 8;
    floatx4 acc1[2] = {fzero, fzero};
    // prefetch registers: [ks] pairs for the current K-chunk
    float4 v0a = *(const float4*)(xrow + 0);
    float4 v1a = *(const float4*)(xrow + 4);
    float4 v0b = *(const float4*)(xrow + 32);
    float4 v1b = *(const float4*)(xrow + 36);
    for (int kc = 0; kc < 8; ++kc) {
        float4 n0a, n1a, n0b, n1b;
        if (kc < 7) {
            const float* nx = xrow + (kc + 1) * 64;
            n0a = *(const float4*)(nx + 0);
            n1a = *(const float4*)(nx + 4);
            n0b = *(const float4*)(nx + 32);
            n1b = *(const float4*)(nx + 36);
        }
#pragma unroll
        for (int ks = 0; ks < 2; ++ks) {
            int kg = kc * 64 + ks * 32 + quad * 8;
            float4 v0 = ks ? v0b : v0a;
            float4 v1 = ks ? v1b : v1a;
            __bf16 e0 = (__bf16)v0.x, e1 = (__bf16)v0.y, e2 = (__bf16)v0.z, e3 = (__bf16)v0.w;
            __bf16 e4 = (__bf16)v1.x, e5 = (__bf16)v1.y, e6 = (__bf16)v1.z, e7 = (__bf16)v1.w;
            bf16x8 ah = {e0, e1, e2, e3, e4, e5, e6, e7};
            bf16x8 al = {(__bf16)(v0.x - (float)e0), (__bf16)(v0.y - (float)e1),
                         (__bf16)(v0.z - (float)e2), (__bf16)(v0.w - (float)e3),
                         (__bf16)(v1.x - (float)e4), (__bf16)(v1.y - (float)e5),
                         (__bf16)(v1.z - (float)e6), (__bf16)(v1.w - (float)e7)};
#pragma unroll
            for (int nt = 0; nt < 2; ++nt) {
                bf16x8 bfr = *(const bf16x8*)(w1T + (nt * 16 + col) * 520 + kg);
                acc1[nt] = __builtin_amdgcn_mfma_f32_16x16x32_bf16(ah, bfr, acc1[nt], 0, 0, 0);
                acc1[nt] = __builtin_amdgcn_mfma_f32_16x16x32_bf16(al, bfr, acc1[nt], 0, 0, 0);
            }
        }
        v0a = n0a; v1a = n1a; v0b = n0b; v1b = n1b;
    }
    __syncthreads();   // all waves done reading w1T

#pragma unroll
    for (int nt = 0; nt < 2; ++nt) {
        float bb = b1[nt * 16 + col];
#pragma unroll
        for (int r = 0; r < 4; ++r)
            h1s[(rbase + r) * 40 + nt * 16 + col] = (__bf16)tanhf(acc1[nt][r] + bb);
    }
    // stage W2^T and Wx^T (region A, w1T dead)
    for (int i = tid; i < 32 * 64; i += 256)  { int k = i >> 6, n = i & 63;  w2T[n * 40 + k] = (__bf16)W2[i]; }
    for (int i = tid; i < 64 * 128; i += 256) { int k = i >> 7, n = i & 127; wxT[n * 72 + k] = (__bf16)Wx[i]; }
    __syncthreads();

    // ---- layer2: h2 = tanh(h1 @ W2 + b2), K=32, N=64 (4 tiles)
    bf16x8 a2 = *(const bf16x8*)(h1s + m * 40 + quad * 8);
    floatx4 acc2[4];
#pragma unroll
    for (int nt = 0; nt < 4; ++nt) {
        bf16x8 bfr = *(const bf16x8*)(w2T + (nt * 16 + col) * 40 + quad * 8);
        acc2[nt] = __builtin_amdgcn_mfma_f32_16x16x32_bf16(a2, bfr, fzero, 0, 0, 0);
    }
#pragma unroll
    for (int nt = 0; nt < 4; ++nt) {
        float bb = b2[nt * 16 + col];
#pragma unroll
        for (int r = 0; r < 4; ++r)
            h2s[(rbase + r) * 72 + nt * 16 + col] = (__bf16)tanhf(acc2[nt][r] + bb);
    }
    // no barrier: each wave reads only its own 16 rows of h2s

    // ---- layer3: xg = h2 @ Wx + bl, K=64 (2 steps), N=128 (8 tiles)
    floatx4 acc3[8];
#pragma unroll
    for (int nt = 0; nt < 8; ++nt) acc3[nt] = fzero;
#pragma unroll
    for (int ks = 0; ks < 2; ++ks) {
        int ko = ks * 32 + quad * 8;
        bf16x8 a3 = *(const bf16x8*)(h2s + m * 72 + ko);
#pragma unroll
        for (int nt = 0; nt < 8; ++nt) {
            bf16x8 bfr = *(const bf16x8*)(wxT + (nt * 16 + col) * 72 + ko);
            acc3[nt] = __builtin_amdgcn_mfma_f32_16x16x32_bf16(a3, bfr, acc3[nt], 0, 0, 0);
        }
    }
#pragma unroll
    for (int nt = 0; nt < 8; ++nt) {
        float bb = bl[nt * 16 + col];
#pragma unroll
        for (int r = 0; r < 4; ++r)
            xg[(size_t)(row0 + rbase + r) * 128 + nt * 16 + col] = acc3[nt][r] + bb;
    }
}

// ---------------------------------------------------------------- kernel 2
// One wave per batch (128 blocks x 64 threads). Lane l owns gates l and l+64
// (Wh columns packed as float2 in 64 VGPRs). h_j lives in lane j (j<32).
// Gate order: [i(0:32) f(32:64) g(64:96) o(96:128)].
//
// R6 vs R4: cross-half broadcast via __builtin_amdgcn_permlane32_swap
// (VALU, no lgkmcnt stall) instead of __shfl/ds_bpermute. Result element [1]
// has lanes 0-31 <- old arg0 lanes 32-63 (the f/o values), lanes 32-63 keep
// their own value — upper-lane c/h stay garbage-but-bounded, never read,
// no feedback into lanes 0-31 (checked: readlane k<32, store l<32).
// Also: tanh(c) tail folded to fma(rcp,2,-1) (one fewer dependent op).
#define RLANE(v, k) __uint_as_float(__builtin_amdgcn_readlane(__float_as_uint(v), (k)))

__global__ __launch_bounds__(64) void k_lstm(
    const float* __restrict__ xg, const float* __restrict__ Wh,
    float* __restrict__ hs)
{
    __shared__ __align__(16) float xbuf[3][32 * 128];   // 48 KB, 3 chunks of 32 steps

    const int b = blockIdx.x;
    const int l = threadIdx.x;
    const float* xgb = xg + (size_t)b * 1024 * 128;
    float* hsb = hs + (size_t)b * 1024 * 32;

    floatx2 wh[32];
#pragma unroll
    for (int k = 0; k < 32; ++k)
        wh[k] = floatx2{Wh[k * 128 + l], Wh[k * 128 + 64 + l]};

    // a1 = (l<32) ? 2*s1-1 : s1  done branch-free: a1 = s1*m1 + c1
    const float sc1 = (l < 32) ? 2.0f : 1.0f;    // tanh(x)=2*sigmoid(2x)-1
    const float m1  = (l < 32) ? 2.0f : 1.0f;
    const float c1  = (l < 32) ? -1.0f : 0.0f;

    // async stage one 32-step chunk (16 KB = 16 x 1KB dwordx4 DMAs)
    auto stage_chunk = [&](int cidx) {
        const float* src = xgb + (size_t)cidx * 4096 + l * 4;
        float* dst = &xbuf[cidx % 3][0];
#pragma unroll
        for (int i = 0; i < 16; ++i)
            __builtin_amdgcn_global_load_lds(src + i * 256, dst + i * 256, 16, 0, 0);
    };

    stage_chunk(0); stage_chunk(1); stage_chunk(2);
    // 48 DMAs outstanding; wait until only chunk2's 16 remain -> chunks 0,1 resident
    asm volatile("s_waitcnt vmcnt(16)" ::: "memory");

    float c = 0.f, h = 0.f;

    // register ring, depth 4, fed from LDS
    float xr0[4], xr1[4];
#pragma unroll
    for (int p = 0; p < 4; ++p) {
        xr0[p] = xbuf[0][p * 128 + l];
        xr1[p] = xbuf[0][p * 128 + 64 + l];
    }

#pragma unroll 1
    for (int ch = 0; ch < 32; ++ch) {
        const float* bufc = xbuf[ch % 3];
        const float* bufn = xbuf[(ch + 1) % 3];
#pragma unroll 1
        for (int s = 0; s < 32; s += 4) {
#pragma unroll
            for (int u = 0; u < 4; ++u) {
                const int tc = ch * 32 + s + u;
                float x0 = xr0[u], x1 = xr1[u];
                // refill ring for step tc+4 (rows 32..35 spill into next chunk's
                // buffer; resident by construction. Last 4 steps load stale data
                // that is never consumed.)
                {
                    int rn = s + u + 4;
                    const float* p = (rn < 32) ? (bufc + rn * 128) : (bufn + (rn - 32) * 128);
                    xr0[u] = p[l];
                    xr1[u] = p[64 + l];
                }
                floatx2 pa = {x0, x1};
                floatx2 pb = {0.f, 0.f}, pc = {0.f, 0.f}, pd = {0.f, 0.f};
#pragma unroll
                for (int k = 0; k < 32; k += 4) {
                    float h0 = RLANE(h, k);
                    float h1 = RLANE(h, k + 1);
                    float h2 = RLANE(h, k + 2);
                    float h3 = RLANE(h, k + 3);
                    pa += wh[k]     * h0;
                    pb += wh[k + 1] * h1;
                    pc += wh[k + 2] * h2;
                    pd += wh[k + 3] * h3;
                }
                floatx2 pe = (pa + pb) + (pc + pd);
                float pre0 = pe.x;                       // i (l<32) / f (l>=32)
                float pre1 = pe.y;                       // g (l<32) / o (l>=32)
                float a0 = __builtin_amdgcn_rcpf(1.0f + __expf(-pre0));       // sigmoid(i|f)
                float s1 = __builtin_amdgcn_rcpf(1.0f + __expf(-sc1 * pre1));
                float a1 = __builtin_fmaf(s1, m1, c1);                        // tanh(g) | sigmoid(o)
                // cross-half broadcast: lanes 0-31 receive lanes 32-63's value.
                uint2v r0 = __builtin_amdgcn_permlane32_swap(
                    __float_as_uint(a0), __float_as_uint(a0), false, false);
                uint2v r1 = __builtin_amdgcn_permlane32_swap(
                    __float_as_uint(a1), __float_as_uint(a1), false, false);
                float f_ = __uint_as_float(r0.y);   // lane j<32 gets f_j
                float o_ = __uint_as_float(r1.y);   // lane j<32 gets o_j
                c = f_ * c + a0 * a1;            // valid in lanes 0-31 (upper: bounded garbage, never read)
                float e = __expf(-2.0f * c);
                float th = __builtin_fmaf(__builtin_amdgcn_rcpf(1.0f + e), 2.0f, -1.0f);
                h = o_ * th;
                if (l < 32) hsb[tc * 32 + l] = h;
            }
        }
        if (ch + 3 < 32) {
            // refill the buffer just vacated (chunk ch's); wait until only those
            // 16 DMAs remain -> chunk ch+2 resident before chunk ch+1's tail
            // prefetch touches it.
            stage_chunk(ch + 3);
            asm volatile("s_waitcnt vmcnt(16)" ::: "memory");
        } else {
            asm volatile("s_waitcnt vmcnt(0)" ::: "memory");
        }
    }
}

// ---------------------------------------------------------------- kernel 3
// 256 rows/block (512 blocks), 4 waves (64 rows each). LDS carve (62464 B):
//  h3s[256][72] @0      (36864)
//  hss[256][40] @36864  (20480)  -> dead after GEMM-W3; w4T[128][76] @36864 (19456)
//  w3T[64][40]  @57344  (5120)
// W4 transpose staged per 128-col chunk with 4k x 4n per thread, ds_write_b64.
// w4T stride 76 -> conflict-free B-frag reads, 4-way (cheap) staging writes.
__global__ __launch_bounds__(256, 2) void k_tail(
    const float* __restrict__ hs, const float* __restrict__ W3, const float* __restrict__ b3,
    const float* __restrict__ W4, const float* __restrict__ b4,
    float* __restrict__ out)
{
    __shared__ __align__(16) char smem[62464];
    __bf16* h3s = (__bf16*)smem;             // [256][72]
    __bf16* hss = (__bf16*)(smem + 36864);   // [256][40]
    __bf16* w4T = (__bf16*)(smem + 36864);   // [128][76] (reuses hss region)
    __bf16* w3T = (__bf16*)(smem + 57344);   // [64][40]

    const int tid  = threadIdx.x;
    const int lane = tid & 63, w = tid >> 6;
    const int quad = lane >> 4, col = lane & 15;
    const int row0 = blockIdx.x * 256;
    const floatx4 fzero = {0.f, 0.f, 0.f, 0.f};

    // stage hs rows (256 x 32 fp32 -> bf16) and W3^T
    for (int i4 = tid; i4 < 2048; i4 += 256) {
        int f = i4 << 2; int r = f >> 5, cc = f & 31;
        float4 v = *(const float4*)(hs + (size_t)(row0 + r) * 32 + cc);
        bf16x4 hv = {(__bf16)v.x, (__bf16)v.y, (__bf16)v.z, (__bf16)v.w};
        *(bf16x4*)(hss + r * 40 + cc) = hv;
    }
    for (int i = tid; i < 32 * 64; i += 256) { int k = i >> 6, n = i & 63; w3T[n * 40 + k] = (__bf16)W3[i]; }
    __syncthreads();

    // ---- h3 = tanh(hs @ W3 + b3), K=32, N=64; 4 m-tiles per wave
#pragma unroll
    for (int mt = 0; mt < 4; ++mt) {
        const int m     = w * 64 + mt * 16 + col;
        const int rbase = w * 64 + mt * 16 + quad * 4;
        bf16x8 a3 = *(const bf16x8*)(hss + m * 40 + quad * 8);
        floatx4 acc3[4];
#pragma unroll
        for (int nt = 0; nt < 4; ++nt) {
            bf16x8 bfr = *(const bf16x8*)(w3T + (nt * 16 + col) * 40 + quad * 8);
            acc3[nt] = __builtin_amdgcn_mfma_f32_16x16x32_bf16(a3, bfr, fzero, 0, 0, 0);
        }
#pragma unroll
        for (int nt = 0; nt < 4; ++nt) {
            float bb = b3[nt * 16 + col];
#pragma unroll
            for (int r = 0; r < 4; ++r)
                h3s[(rbase + r) * 72 + nt * 16 + col] = (__bf16)tanhf(acc3[nt][r] + bb);
        }
    }

    // ---- out = h3 @ W4 + b4, K=64, N=512 in 4 column chunks of 128
    for (int oc = 0; oc < 4; ++oc) {
        __syncthreads();   // prior chunk's B-frag reads (and hss reads, oc=0) done
        // stage w4T[n][k] for this 128-col chunk: 4k x 4n per thread, 2 iters
        for (int it = tid; it < 512; it += 256) {
            int k0 = (it >> 5) << 2;          // 0..60
            int n0 = (it & 31) << 2;          // 0..124
            const float* wp = W4 + (size_t)k0 * 512 + oc * 128 + n0;
            float4 r0 = *(const float4*)(wp);
            float4 r1 = *(const float4*)(wp + 512);
            float4 r2 = *(const float4*)(wp + 1024);
            float4 r3 = *(const float4*)(wp + 1536);
            bf16x4 c0 = {(__bf16)r0.x, (__bf16)r1.x, (__bf16)r2.x, (__bf16)r3.x};
            bf16x4 c1 = {(__bf16)r0.y, (__bf16)r1.y, (__bf16)r2.y, (__bf16)r3.y};
            bf16x4 c2 = {(__bf16)r0.z, (__bf16)r1.z, (__bf16)r2.z, (__bf16)r3.z};
            bf16x4 c3 = {(__bf16)r0.w, (__bf16)r1.w, (__bf16)r2.w, (__bf16)r3.w};
            *(bf16x4*)(w4T + (n0 + 0) * 76 + k0) = c0;
            *(bf16x4*)(w4T + (n0 + 1) * 76 + k0) = c1;
            *(bf16x4*)(w4T + (n0 + 2) * 76 + k0) = c2;
            *(bf16x4*)(w4T + (n0 + 3) * 76 + k0) = c3;
        }
        __syncthreads();

        floatx4 acc4[4][8];
#pragma unroll
        for (int mt = 0; mt < 4; ++mt)
#pragma unroll
            for (int nt = 0; nt < 8; ++nt) acc4[mt][nt] = fzero;
#pragma unroll
        for (int ks = 0; ks < 2; ++ks) {
            int ko = ks * 32 + quad * 8;
#pragma unroll
            for (int mt = 0; mt < 4; ++mt) {
                bf16x8 a4 = *(const bf16x8*)(h3s + (w * 64 + mt * 16 + col) * 72 + ko);
#pragma unroll
                for (int nt = 0; nt < 8; ++nt) {
                    bf16x8 bfr = *(const bf16x8*)(w4T + (nt * 16 + col) * 76 + ko);
                    acc4[mt][nt] = __builtin_amdgcn_mfma_f32_16x16x32_bf16(a4, bfr, acc4[mt][nt], 0, 0, 0);
                }
            }
        }
#pragma unroll
        for (int nt = 0; nt < 8; ++nt) {
            float bb = b4[oc * 128 + nt * 16 + col];
#pragma unroll
            for (int mt = 0; mt < 4; ++mt) {
                const int rbase = row0 + w * 64 + mt * 16 + quad * 4;
#pragma unroll
                for (int r = 0; r < 4; ++r)
                    out[(size_t)(rbase + r) * 512 + oc * 128 + nt * 16 + col] = acc4[mt][nt][r] + bb;
            }
        }
    }
}

// ---------------------------------------------------------------- launch
extern "C" void kernel_launch(void* const* d_in, const int* in_sizes, int n_in,
                              void* d_out, int out_size, void* d_ws, size_t ws_size,
                              hipStream_t stream)
{
    (void)in_sizes; (void)n_in; (void)out_size;
    const float* x  = (const float*)d_in[0];
    const float* W1 = (const float*)d_in[1];
    const float* b1 = (const float*)d_in[2];
    const float* W2 = (const float*)d_in[3];
    const float* b2 = (const float*)d_in[4];
    const float* Wx = (const float*)d_in[5];
    const float* Wh = (const float*)d_in[6];
    const float* bl = (const float*)d_in[7];
    const float* W3 = (const float*)d_in[8];
    const float* b3 = (const float*)d_in[9];
    const float* W4 = (const float*)d_in[10];
    const float* b4 = (const float*)d_in[11];
    float* out = (float*)d_out;

    const size_t hsElems = (size_t)128 * 1024 * 32;    // 16 MB
    const size_t xgElems = (size_t)128 * 1024 * 128;   // 64 MB
    float* hs = (float*)d_ws;
    float* xg = (ws_size >= (hsElems + xgElems) * sizeof(float))
                    ? hs + hsElems
                    : out;   // stash xg in d_out; k3 rewrites d_out only after hs is done

    k_mlp_xg<<<2048, 256, 0, stream>>>(x, W1, b1, W2, b2, Wx, bl, xg);
    k_lstm<<<128, 64, 0, stream>>>(xg, Wh, hs);
    k_tail<<<512, 256, 0, stream>>>(hs, W3, b3, W4, b4, out);
}